// Round 1
// baseline (815.563 us; speedup 1.0000x reference)
//
#include <hip/hip_runtime.h>
#include <stdint.h>

#define S_LEN 2048
#define DMODEL 4096
#define NHEAD 32
#define HDIM 128

typedef __attribute__((ext_vector_type(8))) short bf16x8;
typedef __attribute__((ext_vector_type(4))) float f32x4;

__device__ __forceinline__ unsigned short f2bf(float f) {
    union { float f; unsigned u; } v; v.f = f;
    unsigned u = v.u;
    unsigned r = (u + 0x7FFFu + ((u >> 16) & 1u)) >> 16;   // RNE
    return (unsigned short)r;
}
__device__ __forceinline__ float bf2f(unsigned short h) {
    union { unsigned u; float f; } v; v.u = ((unsigned)h) << 16;
    return v.f;
}

// ---------- elementwise f32 -> bf16 (4 per thread) ----------
__global__ void convert_x_kernel(const float* __restrict__ x,
                                 unsigned short* __restrict__ xb, int n4) {
    int t = blockIdx.x * blockDim.x + threadIdx.x;
    if (t >= n4) return;
    float4 v = ((const float4*)x)[t];
    ushort4 o;
    o.x = f2bf(v.x); o.y = f2bf(v.y); o.z = f2bf(v.z); o.w = f2bf(v.w);
    ((ushort4*)xb)[t] = o;
}

// ---------- transpose+convert weight: w[k][n] f32 -> wt[n][k] bf16 ----------
__global__ void convert_wt_kernel(const float* __restrict__ w,
                                  unsigned short* __restrict__ wt) {
    __shared__ unsigned short t[64][65];
    int n0 = blockIdx.x * 64, k0 = blockIdx.y * 64;
    for (int i = 0; i < 16; ++i) {
        int o = threadIdx.x + i * 256;
        int r = o >> 6, c = o & 63;
        t[r][c] = f2bf(w[(size_t)(k0 + r) * DMODEL + n0 + c]);
    }
    __syncthreads();
    for (int i = 0; i < 16; ++i) {
        int o = threadIdx.x + i * 256;
        int rr = o >> 6, kk = o & 63;
        wt[(size_t)(n0 + rr) * DMODEL + k0 + kk] = t[kk][rr];
    }
}

// ---------- GEMM: C[M,N] = A[M,K] * BT[N,K]^T, bf16 in, fp32 acc ----------
// STORE_MODE: 0 = bf16 row-major, 1 = bf16 transposed C^T[n][m], 2 = fp32 row-major
template<int STORE_MODE>
__global__ __launch_bounds__(256, 2)
void gemm_bt_kernel(const unsigned short* __restrict__ A,
                    const unsigned short* __restrict__ BT,
                    void* __restrict__ C, int M, int N, int K) {
    __shared__ __align__(16) unsigned short As[128 * 32];
    __shared__ __align__(16) unsigned short Bs[128 * 32];
    const int lane = threadIdx.x & 63;
    const int w = threadIdx.x >> 6;
    const int wm = w & 1, wn = w >> 1;
    const int m0 = blockIdx.y * 128, n0 = blockIdx.x * 128;

    f32x4 zero = {0.f, 0.f, 0.f, 0.f};
    f32x4 acc[4][4];
    for (int i = 0; i < 4; ++i)
        for (int j = 0; j < 4; ++j) acc[i][j] = zero;

    const int lr = lane >> 2;   // 0..15: row within a 16-row wave-load
    const int lc = lane & 3;    // 16B chunk within row
    const int q = lane >> 4, lm = lane & 15;

    for (int k0 = 0; k0 < K; k0 += 32) {
        __syncthreads();
        // stage: wave w covers rows [w*32, w*32+32) of As and Bs.
        // LDS chunk c of row r holds global k-chunk (c ^ ((r>>1)&3))  -> 2-way-max
        // bank pattern on the b128 frag reads while keeping lane*16B contiguity.
        for (int i = 0; i < 2; ++i) {
            int rb = w * 32 + i * 16;
            int r = rb + lr;
            int gc = lc ^ ((r >> 1) & 3);
            const unsigned short* ga = A + (size_t)(m0 + r) * K + k0 + gc * 8;
            __builtin_amdgcn_global_load_lds(
                (__attribute__((address_space(1))) unsigned int*)ga,
                (__attribute__((address_space(3))) unsigned int*)(&As[rb * 32]), 16, 0, 0);
            const unsigned short* gb = BT + (size_t)(n0 + r) * K + k0 + gc * 8;
            __builtin_amdgcn_global_load_lds(
                (__attribute__((address_space(1))) unsigned int*)gb,
                (__attribute__((address_space(3))) unsigned int*)(&Bs[rb * 32]), 16, 0, 0);
        }
        __syncthreads();
        bf16x8 af[4], bf[4];
        for (int t = 0; t < 4; ++t) {
            int ra = wm * 64 + t * 16 + lm;
            af[t] = *(const bf16x8*)&As[ra * 32 + ((q ^ ((ra >> 1) & 3)) * 8)];
            int rb2 = wn * 64 + t * 16 + lm;
            bf[t] = *(const bf16x8*)&Bs[rb2 * 32 + ((q ^ ((rb2 >> 1) & 3)) * 8)];
        }
        for (int mi = 0; mi < 4; ++mi)
            for (int ni = 0; ni < 4; ++ni)
                acc[mi][ni] = __builtin_amdgcn_mfma_f32_16x16x32_bf16(
                    af[mi], bf[ni], acc[mi][ni], 0, 0, 0);
    }

    // epilogue: C/D layout col = lane&15, row = (lane>>4)*4 + reg
    for (int mi = 0; mi < 4; ++mi) {
        int mbase = m0 + wm * 64 + mi * 16 + q * 4;
        for (int ni = 0; ni < 4; ++ni) {
            int n = n0 + wn * 64 + ni * 16 + lm;
            if (STORE_MODE == 0) {
                unsigned short* Cb = (unsigned short*)C;
                for (int r = 0; r < 4; ++r)
                    Cb[(size_t)(mbase + r) * N + n] = f2bf(acc[mi][ni][r]);
            } else if (STORE_MODE == 1) {
                unsigned short* Cb = (unsigned short*)C;
                ushort4 v;
                v.x = f2bf(acc[mi][ni][0]); v.y = f2bf(acc[mi][ni][1]);
                v.z = f2bf(acc[mi][ni][2]); v.w = f2bf(acc[mi][ni][3]);
                *(ushort4*)&Cb[(size_t)n * M + mbase] = v;  // mbase % 4 == 0
            } else {
                float* Cf = (float*)C;
                for (int r = 0; r < 4; ++r)
                    Cf[(size_t)(mbase + r) * N + n] = acc[mi][ni][r];
            }
        }
    }
}

// ---------- RoPE in-place on q (fused 1/sqrt(hd)) and k ----------
__global__ void rope_kernel(unsigned short* __restrict__ qb,
                            unsigned short* __restrict__ kb) {
    int t = blockIdx.x * blockDim.x + threadIdx.x;   // S*D/2 pairs
    if (t >= S_LEN * DMODEL / 2) return;
    int s = t >> 11;          // D/2 = 2048 pairs per row
    int p = t & 2047;
    int j = p & 63;           // pair index within head
    // inv_freq = 10000^(-j/64) = 2^(-j * log2(10000)/64)
    float ang = (float)s * exp2f((float)j * -0.2076205059304602f);
    float sn, cs;
    sincosf(ang, &sn, &cs);
    size_t idx = (size_t)s * DMODEL + 2 * p;
    const float SC = 0.08838834764831845f;  // 1/sqrt(128)
    float a0 = bf2f(qb[idx]), a1 = bf2f(qb[idx + 1]);
    qb[idx]     = f2bf((a0 * cs - a1 * sn) * SC);
    qb[idx + 1] = f2bf((a0 * sn + a1 * cs) * SC);
    float b0 = bf2f(kb[idx]), b1 = bf2f(kb[idx + 1]);
    kb[idx]     = f2bf(b0 * cs - b1 * sn);
    kb[idx + 1] = f2bf(b0 * sn + b1 * cs);
}

// ---------- flash attention: 4 waves/block, 16 queries/wave, 32-key chunks ----------
__global__ __launch_bounds__(256, 2)
void attn_kernel(const unsigned short* __restrict__ qb,
                 const unsigned short* __restrict__ kb,
                 const unsigned short* __restrict__ vt,
                 unsigned short* __restrict__ ab) {
    __shared__ __align__(16) unsigned short Ks[32 * 128];   // [key][d], 16B chunks swizzled by key&15
    __shared__ __align__(16) unsigned short VTs[128 * 32];  // [d][key], 16B chunks swizzled by (d>>1)&3
    __shared__ __align__(16) unsigned short Pb[4][16 * 40]; // per-wave P^T staging, pitch 40 (80B)
    const int lane = threadIdx.x & 63;
    const int w = threadIdx.x >> 6;
    const int h = blockIdx.y;
    const int q0 = blockIdx.x * 64;
    const int qw = q0 + w * 16;             // wave's first query
    const int q = lane >> 4, lm = lane & 15;

    bf16x8 qf[4];
    for (int kc = 0; kc < 4; ++kc)
        qf[kc] = *(const bf16x8*)&qb[(size_t)(qw + lm) * DMODEL + h * HDIM + kc * 32 + q * 8];

    f32x4 zero = {0.f, 0.f, 0.f, 0.f};
    f32x4 o[8];
    for (int i = 0; i < 8; ++i) o[i] = zero;
    float mrow[4] = {-1e30f, -1e30f, -1e30f, -1e30f};
    float lrow[4] = {0.f, 0.f, 0.f, 0.f};

    const int nch = q0 / 32 + 2;            // keys 0 .. q0+63
    for (int c = 0; c < nch; ++c) {
        const int j0 = c * 32;
        __syncthreads();
        // stage K chunk: 32 rows x 256B; wave w rows [w*8, w*8+8)
        for (int i = 0; i < 2; ++i) {
            int rb = w * 8 + i * 4;
            int r = rb + (lane >> 4);
            int gc = (lane & 15) ^ (r & 15);
            const unsigned short* g = kb + (size_t)(j0 + r) * DMODEL + h * HDIM + gc * 8;
            __builtin_amdgcn_global_load_lds(
                (__attribute__((address_space(1))) unsigned int*)g,
                (__attribute__((address_space(3))) unsigned int*)(&Ks[rb * 128]), 16, 0, 0);
        }
        // stage V^T chunk: 128 rows x 64B; wave w rows [w*32, w*32+32)
        for (int i = 0; i < 2; ++i) {
            int db = w * 32 + i * 16;
            int d = db + (lane >> 2);
            int gc = (lane & 3) ^ ((d >> 1) & 3);
            const unsigned short* g = vt + (size_t)(h * HDIM + d) * S_LEN + j0 + gc * 8;
            __builtin_amdgcn_global_load_lds(
                (__attribute__((address_space(1))) unsigned int*)g,
                (__attribute__((address_space(3))) unsigned int*)(&VTs[db * 32]), 16, 0, 0);
        }
        __syncthreads();
        if (j0 > qw + 15) continue;   // wave-uniform; barriers stay matched

        // S = Q K^T, two 16-key subtiles
        f32x4 s0 = zero, s1 = zero;
        for (int kc = 0; kc < 4; ++kc) {
            bf16x8 kf0 = *(const bf16x8*)&Ks[lm * 128 + (((kc * 4 + q) ^ lm) * 8)];
            int kk1 = 16 + lm;
            bf16x8 kf1 = *(const bf16x8*)&Ks[kk1 * 128 + (((kc * 4 + q) ^ lm) * 8)];
            s0 = __builtin_amdgcn_mfma_f32_16x16x32_bf16(qf[kc], kf0, s0, 0, 0, 0);
            s1 = __builtin_amdgcn_mfma_f32_16x16x32_bf16(qf[kc], kf1, s1, 0, 0, 0);
        }
        // causal mask (scores already scaled via q)
        if (j0 + 31 > qw) {
            for (int r = 0; r < 4; ++r) {
                int qq = qw + q * 4 + r;
                if (j0 + lm > qq)      s0[r] = -1e30f;
                if (j0 + 16 + lm > qq) s1[r] = -1e30f;
            }
        }
        // online softmax; row r lives on the 16 lanes of this quad-group
        float al[4], p0[4], p1[4];
        for (int r = 0; r < 4; ++r) {
            float mx = fmaxf(s0[r], s1[r]);
            mx = fmaxf(mx, __shfl_xor(mx, 1));
            mx = fmaxf(mx, __shfl_xor(mx, 2));
            mx = fmaxf(mx, __shfl_xor(mx, 4));
            mx = fmaxf(mx, __shfl_xor(mx, 8));
            float mn = fmaxf(mrow[r], mx);
            al[r] = __expf(mrow[r] - mn);
            mrow[r] = mn;
            p0[r] = __expf(s0[r] - mn);
            p1[r] = __expf(s1[r] - mn);
            float rs = p0[r] + p1[r];
            rs += __shfl_xor(rs, 1);
            rs += __shfl_xor(rs, 2);
            rs += __shfl_xor(rs, 4);
            rs += __shfl_xor(rs, 8);
            lrow[r] = lrow[r] * al[r] + rs;
        }
        // P: C/D layout -> LDS -> A-operand layout (per-wave, in-wave ordering ok)
        for (int r = 0; r < 4; ++r) {
            Pb[w][(q * 4 + r) * 40 + lm]      = f2bf(p0[r]);
            Pb[w][(q * 4 + r) * 40 + 16 + lm] = f2bf(p1[r]);
        }
        bf16x8 pA = *(const bf16x8*)&Pb[w][lm * 40 + q * 8];
        for (int nt = 0; nt < 8; ++nt) {
            int d = lm + nt * 16;
            bf16x8 vf = *(const bf16x8*)&VTs[d * 32 + ((q ^ ((d >> 1) & 3)) * 8)];
            f32x4 oo = o[nt];
            for (int r = 0; r < 4; ++r) oo[r] *= al[r];
            o[nt] = __builtin_amdgcn_mfma_f32_16x16x32_bf16(pA, vf, oo, 0, 0, 0);
        }
    }
    float inv[4];
    for (int r = 0; r < 4; ++r) inv[r] = 1.0f / lrow[r];
    for (int nt = 0; nt < 8; ++nt) {
        int d = h * HDIM + lm + nt * 16;
        for (int r = 0; r < 4; ++r)
            ab[(size_t)(qw + q * 4 + r) * DMODEL + d] = f2bf(o[nt][r] * inv[r]);
    }
}

extern "C" void kernel_launch(void* const* d_in, const int* in_sizes, int n_in,
                              void* d_out, int out_size, void* d_ws, size_t ws_size,
                              hipStream_t stream) {
    const float* x  = (const float*)d_in[0];
    const float* wq = (const float*)d_in[1];
    const float* wk = (const float*)d_in[2];
    const float* wv = (const float*)d_in[3];
    const float* wo = (const float*)d_in[4];
    char* ws = (char*)d_ws;
    const size_t MB = 1024 * 1024;
    unsigned short* xb  = (unsigned short*)(ws + 0 * MB);   // 16 MB  x bf16
    unsigned short* qb  = (unsigned short*)(ws + 16 * MB);  // 16 MB  q bf16 [s][h*hd+d]
    unsigned short* kb  = (unsigned short*)(ws + 32 * MB);  // 16 MB  k bf16 [s][h*hd+d]
    unsigned short* vtb = (unsigned short*)(ws + 48 * MB);  // 16 MB  v^T bf16 [h*hd+d][s]
    unsigned short* ab  = (unsigned short*)(ws + 64 * MB);  // 16 MB  attn bf16 [s][h*hd+d]
    unsigned short* wtb = (unsigned short*)(ws + 80 * MB);  // 32 MB  reused weight^T bf16

    dim3 cg(64, 64);   // weight convert tiles
    dim3 gg(32, 16);   // gemm: N/128 x M/128

    convert_x_kernel<<<(S_LEN * DMODEL / 4) / 256, 256, 0, stream>>>(x, xb, S_LEN * DMODEL / 4);

    convert_wt_kernel<<<cg, 256, 0, stream>>>(wq, wtb);
    gemm_bt_kernel<0><<<gg, 256, 0, stream>>>(xb, wtb, qb, S_LEN, DMODEL, DMODEL);
    convert_wt_kernel<<<cg, 256, 0, stream>>>(wk, wtb);
    gemm_bt_kernel<0><<<gg, 256, 0, stream>>>(xb, wtb, kb, S_LEN, DMODEL, DMODEL);
    convert_wt_kernel<<<cg, 256, 0, stream>>>(wv, wtb);
    gemm_bt_kernel<1><<<gg, 256, 0, stream>>>(xb, wtb, vtb, S_LEN, DMODEL, DMODEL);

    rope_kernel<<<(S_LEN * DMODEL / 2) / 256, 256, 0, stream>>>(qb, kb);

    attn_kernel<<<dim3(S_LEN / 64, NHEAD), 256, 0, stream>>>(qb, kb, vtb, ab);

    convert_wt_kernel<<<cg, 256, 0, stream>>>(wo, wtb);
    gemm_bt_kernel<2><<<gg, 256, 0, stream>>>(ab, wtb, d_out, S_LEN, DMODEL, DMODEL);
}

// Round 2
// 801.853 us; speedup vs baseline: 1.0171x; 1.0171x over previous
//
#include <hip/hip_runtime.h>
#include <stdint.h>

#define S_LEN 2048
#define DMODEL 4096
#define NHEAD 32
#define HDIM 128

typedef __attribute__((ext_vector_type(8))) short bf16x8;
typedef __attribute__((ext_vector_type(4))) float f32x4;

__device__ __forceinline__ unsigned short f2bf(float f) {
    union { float f; unsigned u; } v; v.f = f;
    unsigned u = v.u;
    unsigned r = (u + 0x7FFFu + ((u >> 16) & 1u)) >> 16;   // RNE
    return (unsigned short)r;
}
__device__ __forceinline__ float bf2f(unsigned short h) {
    union { unsigned u; float f; } v; v.u = ((unsigned)h) << 16;
    return v.f;
}

// ---------- elementwise f32 -> bf16 (4 per thread) ----------
__global__ void convert_x_kernel(const float* __restrict__ x,
                                 unsigned short* __restrict__ xb, int n4) {
    int t = blockIdx.x * blockDim.x + threadIdx.x;
    if (t >= n4) return;
    float4 v = ((const float4*)x)[t];
    ushort4 o;
    o.x = f2bf(v.x); o.y = f2bf(v.y); o.z = f2bf(v.z); o.w = f2bf(v.w);
    ((ushort4*)xb)[t] = o;
}

// ---------- transpose+convert weight: w[k][n] f32 -> wt[n][k] bf16 ----------
__global__ void convert_wt_kernel(const float* __restrict__ w,
                                  unsigned short* __restrict__ wt) {
    __shared__ unsigned short t[64][65];
    int n0 = blockIdx.x * 64, k0 = blockIdx.y * 64;
    for (int i = 0; i < 16; ++i) {
        int o = threadIdx.x + i * 256;
        int r = o >> 6, c = o & 63;
        t[r][c] = f2bf(w[(size_t)(k0 + r) * DMODEL + n0 + c]);
    }
    __syncthreads();
    for (int i = 0; i < 16; ++i) {
        int o = threadIdx.x + i * 256;
        int rr = o >> 6, kk = o & 63;
        wt[(size_t)(n0 + rr) * DMODEL + k0 + kk] = t[kk][rr];
    }
}

// ---------- GEMM: C[M,N] = A[M,K] * BT[N,K]^T, bf16 in, fp32 acc ----------
// STORE_MODE: 0 = bf16 row-major, 1 = bf16 transposed C^T[n][m], 2 = fp32 row-major
template<int STORE_MODE>
__global__ __launch_bounds__(256, 2)
void gemm_bt_kernel(const unsigned short* __restrict__ A,
                    const unsigned short* __restrict__ BT,
                    void* __restrict__ C, int M, int N, int K) {
    __shared__ __align__(16) unsigned short As[128 * 32];
    __shared__ __align__(16) unsigned short Bs[128 * 32];
    const int lane = threadIdx.x & 63;
    const int w = threadIdx.x >> 6;
    const int wm = w & 1, wn = w >> 1;
    const int m0 = blockIdx.y * 128, n0 = blockIdx.x * 128;

    f32x4 zero = {0.f, 0.f, 0.f, 0.f};
    f32x4 acc[4][4];
    for (int i = 0; i < 4; ++i)
        for (int j = 0; j < 4; ++j) acc[i][j] = zero;

    const int lr = lane >> 2;   // 0..15: row within a 16-row wave-load
    const int lc = lane & 3;    // 16B chunk within row
    const int q = lane >> 4, lm = lane & 15;

    for (int k0 = 0; k0 < K; k0 += 32) {
        __syncthreads();
        for (int i = 0; i < 2; ++i) {
            int rb = w * 32 + i * 16;
            int r = rb + lr;
            int gc = lc ^ ((r >> 1) & 3);
            const unsigned short* ga = A + (size_t)(m0 + r) * K + k0 + gc * 8;
            __builtin_amdgcn_global_load_lds(
                (__attribute__((address_space(1))) unsigned int*)ga,
                (__attribute__((address_space(3))) unsigned int*)(&As[rb * 32]), 16, 0, 0);
            const unsigned short* gb = BT + (size_t)(n0 + r) * K + k0 + gc * 8;
            __builtin_amdgcn_global_load_lds(
                (__attribute__((address_space(1))) unsigned int*)gb,
                (__attribute__((address_space(3))) unsigned int*)(&Bs[rb * 32]), 16, 0, 0);
        }
        __syncthreads();
        bf16x8 af[4], bf[4];
        for (int t = 0; t < 4; ++t) {
            int ra = wm * 64 + t * 16 + lm;
            af[t] = *(const bf16x8*)&As[ra * 32 + ((q ^ ((ra >> 1) & 3)) * 8)];
            int rb2 = wn * 64 + t * 16 + lm;
            bf[t] = *(const bf16x8*)&Bs[rb2 * 32 + ((q ^ ((rb2 >> 1) & 3)) * 8)];
        }
        for (int mi = 0; mi < 4; ++mi)
            for (int ni = 0; ni < 4; ++ni)
                acc[mi][ni] = __builtin_amdgcn_mfma_f32_16x16x32_bf16(
                    af[mi], bf[ni], acc[mi][ni], 0, 0, 0);
    }

    for (int mi = 0; mi < 4; ++mi) {
        int mbase = m0 + wm * 64 + mi * 16 + q * 4;
        for (int ni = 0; ni < 4; ++ni) {
            int n = n0 + wn * 64 + ni * 16 + lm;
            if (STORE_MODE == 0) {
                unsigned short* Cb = (unsigned short*)C;
                for (int r = 0; r < 4; ++r)
                    Cb[(size_t)(mbase + r) * N + n] = f2bf(acc[mi][ni][r]);
            } else if (STORE_MODE == 1) {
                unsigned short* Cb = (unsigned short*)C;
                ushort4 v;
                v.x = f2bf(acc[mi][ni][0]); v.y = f2bf(acc[mi][ni][1]);
                v.z = f2bf(acc[mi][ni][2]); v.w = f2bf(acc[mi][ni][3]);
                *(ushort4*)&Cb[(size_t)n * M + mbase] = v;
            } else {
                float* Cf = (float*)C;
                for (int r = 0; r < 4; ++r)
                    Cf[(size_t)(mbase + r) * N + n] = acc[mi][ni][r];
            }
        }
    }
}

// ---------- RoPE in-place on q (fused 1/sqrt(hd)) and k ----------
__global__ void rope_kernel(unsigned short* __restrict__ qb,
                            unsigned short* __restrict__ kb) {
    int t = blockIdx.x * blockDim.x + threadIdx.x;   // S*D/2 pairs
    if (t >= S_LEN * DMODEL / 2) return;
    int s = t >> 11;
    int p = t & 2047;
    int j = p & 63;
    float ang = (float)s * exp2f((float)j * -0.2076205059304602f);
    float sn, cs;
    sincosf(ang, &sn, &cs);
    size_t idx = (size_t)s * DMODEL + 2 * p;
    const float SC = 0.08838834764831845f;  // 1/sqrt(128)
    float a0 = bf2f(qb[idx]), a1 = bf2f(qb[idx + 1]);
    qb[idx]     = f2bf((a0 * cs - a1 * sn) * SC);
    qb[idx + 1] = f2bf((a0 * sn + a1 * cs) * SC);
    float b0 = bf2f(kb[idx]), b1 = bf2f(kb[idx + 1]);
    kb[idx]     = f2bf(b0 * cs - b1 * sn);
    kb[idx + 1] = f2bf(b0 * sn + b1 * cs);
}

// ---------- flash attention v2: 64-key chunks, register-prefetch staging ----------
// Block = 4 waves x 16 queries = 64 queries, one head. Chunk = 64 keys.
// Pipeline: global->VGPR prefetch of chunk c+1 issued before compute(c);
// barrier; ds_write regs->LDS; barrier. The vmcnt drain at the first barrier
// is satisfied during compute -> no exposed global latency.
__global__ __launch_bounds__(256, 2)
void attn_kernel(const unsigned short* __restrict__ qb,
                 const unsigned short* __restrict__ kb,
                 const unsigned short* __restrict__ vt,
                 unsigned short* __restrict__ ab) {
    __shared__ __align__(16) unsigned short Ks[64 * 128];   // [key][d], chunk c' = c ^ (key&15)
    __shared__ __align__(16) unsigned short VTs[128 * 64];  // [d][key], chunk c' = c ^ (d&7)
    __shared__ __align__(16) unsigned short Pb[4][16 * 72]; // per-wave P staging, pitch 72
    const int t = threadIdx.x;
    const int lane = t & 63;
    const int w = t >> 6;
    const int h = blockIdx.y;
    const int q0 = ((int)gridDim.x - 1 - (int)blockIdx.x) * 64;  // longest blocks first
    const int qw = q0 + w * 16;
    const int q = lane >> 4, lm = lane & 15;

    // staging assignment (fixed per thread)
    const int krow = t >> 2;            // 0..63  (key row)
    const int kcol = t & 3;             // +i*4 -> 16 chunks/row
    const int vrow = t >> 1;            // 0..127 (d row)
    const int vcol = t & 1;             // +i*2 -> 8 chunks/row

    const unsigned short* gK = kb + (size_t)krow * DMODEL + h * HDIM;
    const unsigned short* gV = vt + (size_t)(h * HDIM + vrow) * S_LEN;

    bf16x8 qf[4];
    for (int kc = 0; kc < 4; ++kc)
        qf[kc] = *(const bf16x8*)&qb[(size_t)(qw + lm) * DMODEL + h * HDIM + kc * 32 + q * 8];

    f32x4 zero = {0.f, 0.f, 0.f, 0.f};
    f32x4 o[8];
    for (int i = 0; i < 8; ++i) o[i] = zero;
    float mrow[4] = {-1e30f, -1e30f, -1e30f, -1e30f};
    float lrow[4] = {0.f, 0.f, 0.f, 0.f};

    const int nch = q0 / 64 + 1;

    bf16x8 kreg[4], vreg[4];
    // prologue: stage chunk 0
    for (int i = 0; i < 4; ++i) {
        kreg[i] = *(const bf16x8*)&gK[(size_t)0 * DMODEL + (kcol + i * 4) * 8];
        vreg[i] = *(const bf16x8*)&gV[0 + (vcol + i * 2) * 8];
    }
    for (int i = 0; i < 4; ++i) {
        *(bf16x8*)&Ks[krow * 128 + (((kcol + i * 4) ^ (krow & 15)) * 8)] = kreg[i];
        *(bf16x8*)&VTs[vrow * 64 + (((vcol + i * 2) ^ (vrow & 7)) * 8)] = vreg[i];
    }
    __syncthreads();

    for (int c = 0; c < nch; ++c) {
        const int j0 = c * 64;
        // prefetch next chunk into registers (latency hidden behind compute)
        if (c + 1 < nch) {
            const size_t jn = (size_t)(j0 + 64);
            for (int i = 0; i < 4; ++i) {
                kreg[i] = *(const bf16x8*)&gK[jn * DMODEL + (kcol + i * 4) * 8];
                vreg[i] = *(const bf16x8*)&gV[jn + (vcol + i * 2) * 8];
            }
        }

        // ---- compute chunk c ----
        f32x4 s[4];
        for (int ks = 0; ks < 4; ++ks) s[ks] = zero;
        for (int kc = 0; kc < 4; ++kc)
            for (int ks = 0; ks < 4; ++ks) {
                bf16x8 kf = *(const bf16x8*)&Ks[(ks * 16 + lm) * 128 + (((kc * 4 + q) ^ lm) * 8)];
                s[ks] = __builtin_amdgcn_mfma_f32_16x16x32_bf16(qf[kc], kf, s[ks], 0, 0, 0);
            }
        if (c == nch - 1) {
            for (int ks = 0; ks < 4; ++ks)
                for (int r = 0; r < 4; ++r)
                    if (j0 + ks * 16 + lm > qw + q * 4 + r) s[ks][r] = -1e30f;
        }
        float al[4];
        for (int r = 0; r < 4; ++r) {
            float mx = fmaxf(fmaxf(s[0][r], s[1][r]), fmaxf(s[2][r], s[3][r]));
            mx = fmaxf(mx, __shfl_xor(mx, 1));
            mx = fmaxf(mx, __shfl_xor(mx, 2));
            mx = fmaxf(mx, __shfl_xor(mx, 4));
            mx = fmaxf(mx, __shfl_xor(mx, 8));
            float mn = fmaxf(mrow[r], mx);
            al[r] = __expf(mrow[r] - mn);
            mrow[r] = mn;
            float rs = 0.f;
            float pv[4];
            for (int ks = 0; ks < 4; ++ks) {
                pv[ks] = __expf(s[ks][r] - mn);
                rs += pv[ks];
            }
            rs += __shfl_xor(rs, 1);
            rs += __shfl_xor(rs, 2);
            rs += __shfl_xor(rs, 4);
            rs += __shfl_xor(rs, 8);
            lrow[r] = lrow[r] * al[r] + rs;
            for (int ks = 0; ks < 4; ++ks)
                Pb[w][(q * 4 + r) * 72 + ks * 16 + lm] = f2bf(pv[ks]);
        }
        bf16x8 pA0 = *(const bf16x8*)&Pb[w][lm * 72 + q * 8];
        bf16x8 pA1 = *(const bf16x8*)&Pb[w][lm * 72 + 32 + q * 8];
        for (int nt = 0; nt < 8; ++nt) {
            int d = nt * 16 + lm;
            bf16x8 vf0 = *(const bf16x8*)&VTs[d * 64 + ((q ^ (d & 7)) * 8)];
            bf16x8 vf1 = *(const bf16x8*)&VTs[d * 64 + (((4 + q) ^ (d & 7)) * 8)];
            f32x4 oo = o[nt];
            for (int r = 0; r < 4; ++r) oo[r] *= al[r];
            oo = __builtin_amdgcn_mfma_f32_16x16x32_bf16(pA0, vf0, oo, 0, 0, 0);
            o[nt] = __builtin_amdgcn_mfma_f32_16x16x32_bf16(pA1, vf1, oo, 0, 0, 0);
        }

        __syncthreads();   // all waves done reading LDS chunk c
        if (c + 1 < nch) {
            for (int i = 0; i < 4; ++i) {
                *(bf16x8*)&Ks[krow * 128 + (((kcol + i * 4) ^ (krow & 15)) * 8)] = kreg[i];
                *(bf16x8*)&VTs[vrow * 64 + (((vcol + i * 2) ^ (vrow & 7)) * 8)] = vreg[i];
            }
        }
        __syncthreads();   // staging visible
    }

    float inv[4];
    for (int r = 0; r < 4; ++r) inv[r] = 1.0f / lrow[r];
    for (int nt = 0; nt < 8; ++nt) {
        int d = h * HDIM + lm + nt * 16;
        for (int r = 0; r < 4; ++r)
            ab[(size_t)(qw + q * 4 + r) * DMODEL + d] = f2bf(o[nt][r] * inv[r]);
    }
}

extern "C" void kernel_launch(void* const* d_in, const int* in_sizes, int n_in,
                              void* d_out, int out_size, void* d_ws, size_t ws_size,
                              hipStream_t stream) {
    const float* x  = (const float*)d_in[0];
    const float* wq = (const float*)d_in[1];
    const float* wk = (const float*)d_in[2];
    const float* wv = (const float*)d_in[3];
    const float* wo = (const float*)d_in[4];
    char* ws = (char*)d_ws;
    const size_t MB = 1024 * 1024;
    unsigned short* xb  = (unsigned short*)(ws + 0 * MB);
    unsigned short* qb  = (unsigned short*)(ws + 16 * MB);
    unsigned short* kb  = (unsigned short*)(ws + 32 * MB);
    unsigned short* vtb = (unsigned short*)(ws + 48 * MB);
    unsigned short* ab  = (unsigned short*)(ws + 64 * MB);
    unsigned short* wtb = (unsigned short*)(ws + 80 * MB);

    dim3 cg(64, 64);
    dim3 gg(32, 16);

    convert_x_kernel<<<(S_LEN * DMODEL / 4) / 256, 256, 0, stream>>>(x, xb, S_LEN * DMODEL / 4);

    convert_wt_kernel<<<cg, 256, 0, stream>>>(wq, wtb);
    gemm_bt_kernel<0><<<gg, 256, 0, stream>>>(xb, wtb, qb, S_LEN, DMODEL, DMODEL);
    convert_wt_kernel<<<cg, 256, 0, stream>>>(wk, wtb);
    gemm_bt_kernel<0><<<gg, 256, 0, stream>>>(xb, wtb, kb, S_LEN, DMODEL, DMODEL);
    convert_wt_kernel<<<cg, 256, 0, stream>>>(wv, wtb);
    gemm_bt_kernel<1><<<gg, 256, 0, stream>>>(xb, wtb, vtb, S_LEN, DMODEL, DMODEL);

    rope_kernel<<<(S_LEN * DMODEL / 2) / 256, 256, 0, stream>>>(qb, kb);

    attn_kernel<<<dim3(S_LEN / 64, NHEAD), 256, 0, stream>>>(qb, kb, vtb, ab);

    convert_wt_kernel<<<cg, 256, 0, stream>>>(wo, wtb);
    gemm_bt_kernel<2><<<gg, 256, 0, stream>>>(ab, wtb, d_out, S_LEN, DMODEL, DMODEL);
}